// Round 12
// baseline (154.643 us; speedup 1.0000x reference)
//
#include <hip/hip_runtime.h>
#include <math.h>

typedef _Float16 f16;
typedef f16 f16x8 __attribute__((ext_vector_type(8)));
typedef float f32x16 __attribute__((ext_vector_type(16)));
typedef unsigned short u16;
typedef unsigned int u32;

#define B_ 2
#define C_ 64
#define KS 5             // K-steps of 16: 64 feats + mask(k=64) + bias(k=65) + pad
#define H_ 112
#define W_ 112
#define N_ 12544
#define S_ 50
#define G_ 120
#define MT 392           // m-tiles of 32
#define NT 392           // n-subtiles of 32
#define SPLIT 8
#define TPS 49           // m-tiles per split
#define LCAP 4           // per-lane-half top-4 (exact, branch-free)
#define CPR (SPLIT*2*LCAP) // 64 candidates per row -> 1 per lane in rescore

#define NEGINF (-__builtin_inff())
#define FMED3 __builtin_amdgcn_fmed3f

union U16B { uint4 u; f16x8 h; f16 e[8]; };

// ---------------------------------------------------------------------------
// Kernel 0: bool-mask format detect (byte vs int32), vectorized word test.
// ---------------------------------------------------------------------------
__global__ void detect_fmt(const u32* __restrict__ m1, const u32* __restrict__ m2,
                           int nw, int* __restrict__ flags) {
    __shared__ u32 s[2];
    if (threadIdx.x == 0) { s[0] = 0; s[1] = 0; }
    __syncthreads();
    u32 a = 0, bb = 0;
    for (int i = threadIdx.x; i < nw; i += blockDim.x) {
        a  |= m1[i] & 0xFFFFFF00u;
        bb |= m2[i] & 0xFFFFFF00u;
    }
    if (a)  atomicOr(&s[0], 1u);
    if (bb) atomicOr(&s[1], 1u);
    __syncthreads();
    if (threadIdx.x == 0) { flags[0] = s[0] ? 1 : 0; flags[1] = s[1] ? 1 : 0; }
}

// ---------------------------------------------------------------------------
// Kernel 1 (fused): y==0 -> src features: fp16 frag-ordered fxq (k=64/65
// channels = 1.0) AND contiguous fp32 fxT rows. y==1 -> dst features: fp32
// fynT rows (bitwise same math as round 1), fp16 frag-ordered fynq with
// mask channel (k=64: 0 valid / -96 masked) and bias channel (k=65: +128),
// nyeps, minf.
// ---------------------------------------------------------------------------
__global__ void prep(const float* __restrict__ fx, const float* __restrict__ fy,
                     const unsigned char* __restrict__ mask2b,
                     const int* __restrict__ flags,
                     f16* __restrict__ fxq, float* __restrict__ fxT,
                     float* __restrict__ fynT, f16* __restrict__ fynq,
                     float* __restrict__ nyeps, float* __restrict__ minf) {
    int t = blockIdx.x * blockDim.x + threadIdx.x;   // t = b*N + pixel
    if (t >= B_ * N_) return;
    int b = t / N_, m = t - b * N_;
    int tile = m >> 5, r = m & 31;

    if (blockIdx.y == 0) {
        const float* src = fx + (size_t)b * C_ * N_ + m;
        float v[64];
        #pragma unroll
        for (int c = 0; c < C_; ++c) v[c] = src[(size_t)c * N_];

        float4* xT = (float4*)(fxT + (size_t)t * C_);
        #pragma unroll
        for (int c4 = 0; c4 < 16; ++c4)
            xT[c4] = make_float4(v[c4*4], v[c4*4+1], v[c4*4+2], v[c4*4+3]);

        uint4* q4 = (uint4*)fxq;
        size_t cb = (size_t)(b * NT + tile) * KS * 64;
        #pragma unroll
        for (int ks = 0; ks < KS; ++ks) {
            #pragma unroll
            for (int hi = 0; hi < 2; ++hi) {
                U16B tmp;
                #pragma unroll
                for (int i = 0; i < 8; ++i) {
                    int k = 16 * ks + 8 * hi + i;
                    float val = (k < 64) ? v[k] : ((k <= 65) ? 1.0f : 0.0f);
                    tmp.e[i] = (f16)val;
                }
                q4[cb + (size_t)ks * 64 + hi * 32 + r] = tmp.u;
            }
        }
    } else {
        const float* src = fy + (size_t)b * C_ * N_ + m;
        float v[64];
        float ss = 0.f;
        #pragma unroll
        for (int c = 0; c < C_; ++c) { v[c] = src[(size_t)c * N_]; ss = fmaf(v[c], v[c], ss); }
        float ny = sqrtf(ss) + 1e-12f;
        nyeps[t] = ny;
        bool valid = flags[1] ? (mask2b[t] != 0) : (((const int*)mask2b)[t] != 0);
        minf[t] = valid ? 0.0f : NEGINF;
        float mval = valid ? 0.0f : -96.0f;

        float* dT = fynT + (size_t)t * C_;
        #pragma unroll
        for (int c = 0; c < C_; ++c) dT[c] = v[c] / ny;   // round-1 arithmetic

        uint4* q4 = (uint4*)fynq;
        size_t cb = (size_t)(b * MT + tile) * KS * 64;
        #pragma unroll
        for (int ks = 0; ks < KS; ++ks) {
            #pragma unroll
            for (int hi = 0; hi < 2; ++hi) {
                U16B tmp;
                #pragma unroll
                for (int i = 0; i < 8; ++i) {
                    int k = 16 * ks + 8 * hi + i;
                    float val = (k < 64) ? (v[k] / ny)
                              : ((k == 64) ? mval : ((k == 65) ? 128.0f : 0.0f));
                    tmp.e[i] = (f16)val;
                }
                q4[cb + (size_t)ks * 64 + hi * 32 + r] = tmp.u;
            }
        }
    }
}

// ---------------------------------------------------------------------------
// Kernel 2: MFMA candidate pass. Wave-granular (3136 x 128, panel = gid&15
// for XCD L2 affinity). MFMAs issued via INLINE ASM with "v" constraints:
// accumulators/operands are FORCED into architectural VGPRs (R10/R11's
// VGPR_Count 44-60 proved the builtin path AGPR-ized ~90 regs -> accvgpr
// copy churn + hidden occupancy cap at ~3 waves/SIMD). Single A buffer
// (WAR-ordered vs issued MFMAs) + ping-pong accumulators: >=5 MFMAs (~160
// cyc) separate an acc's last write from its first VALU read, so no MFMA->
// VALU hazard exposure. 4 independent med3 top-4 chains (reg r -> chain
// r&3), merged once at the end == exact stream top-4, candidate set
// bit-identical to R10/R11. 10-bit (tile*16+reg) index packed into mantissa
// low bits (scores positive via +128 bias channel -> f32 order == u32
// order). ~119 live VGPRs -> launch_bounds(128,4) = 4 waves/SIMD.
// ---------------------------------------------------------------------------
#define LDA(dst, t) { _Pragma("unroll") \
    for (int ks = 0; ks < KS; ++ks) { \
        U16B u_; u_.u = fyb[((size_t)(t) * KS + ks) * 64]; dst[ks] = u_.h; } }

#define MFMAC(acc, a) { \
    asm("v_mfma_f32_32x32x16_f16 %0, %1, %2, %3" \
        : "=v"(acc) : "v"(a[0]), "v"(bfr[0]), "v"(zvec)); \
    asm("v_mfma_f32_32x32x16_f16 %0, %1, %2, %0" \
        : "+v"(acc) : "v"(a[1]), "v"(bfr[1])); \
    asm("v_mfma_f32_32x32x16_f16 %0, %1, %2, %0" \
        : "+v"(acc) : "v"(a[2]), "v"(bfr[2])); \
    asm("v_mfma_f32_32x32x16_f16 %0, %1, %2, %0" \
        : "+v"(acc) : "v"(a[3]), "v"(bfr[3])); \
    asm("v_mfma_f32_32x32x16_f16 %0, %1, %2, %0" \
        : "+v"(acc) : "v"(a[4]), "v"(bfr[4])); }

#define EXTRACT(acc, bse) { \
    _Pragma("unroll") \
    for (int r = 0; r < 16; ++r) { \
        const int c_ = r & 3; \
        u32 pb_ = (__float_as_uint(acc[r]) & VMASK) | ((bse) + (u32)r); \
        float p_ = __uint_as_float(pb_); \
        ch4[c_] = FMED3(p_, ch3[c_], ch4[c_]); \
        ch3[c_] = FMED3(p_, ch2[c_], ch3[c_]); \
        ch2[c_] = FMED3(p_, ch1[c_], ch2[c_]); \
        ch1[c_] = fmaxf(p_, ch1[c_]); } }

__global__ __launch_bounds__(128, 4)
void stage1(const f16* __restrict__ fxq, const f16* __restrict__ fynq,
            u32* __restrict__ cvals, u16* __restrict__ cidx) {
    const int tid = threadIdx.x;
    const int lane = tid & 63, w = tid >> 6;
    const int lo = lane & 31, hi = lane >> 5;
    const int gid = blockIdx.x;          // 0..3135
    const int panel = gid & 15;          // (b<<3)|split -> XCD affinity
    const int b = panel >> 3, split = panel & 7;
    const int nt = (gid >> 4) * 2 + w;   // 0..391
    const int tbase = split * TPS;

    const uint4* fxq4 = (const uint4*)fxq;
    const uint4* fyb  = (const uint4*)fynq + ((size_t)(b * MT + tbase) * KS) * 64 + lane;

    // pack mask pinned in a VGPR so (bits & VMASK) | s_idx fuses to v_and_or_b32
    u32 VMASK;
    asm("v_mov_b32 %0, 0xFFFFFC00" : "=v"(VMASK));

    // resident B-fragments: fx for this wave's n-subtile
    f16x8 bfr[KS];
    #pragma unroll
    for (int ks = 0; ks < KS; ++ks) {
        U16B u; u.u = fxq4[((size_t)((b * NT + nt) * KS + ks)) * 64 + lane];
        bfr[ks] = u.h;
    }

    f32x16 zvec = {};   // loop-invariant C operand: no per-cell acc re-init

    // 4 independent top-4 chains (reg r -> chain r&3)
    float ch1[4] = {0.f, 0.f, 0.f, 0.f};
    float ch2[4] = {0.f, 0.f, 0.f, 0.f};
    float ch3[4] = {0.f, 0.f, 0.f, 0.f};
    float ch4[4] = {0.f, 0.f, 0.f, 0.f};

    f16x8 aA[KS];
    f32x16 accA, accB;

    LDA(aA, 0);
    MFMAC(accA, aA);                     // cell 0 in flight
    LDA(aA, 1);                          // WAR-ordered after cell 0's issue

    #pragma unroll 1
    for (int t = 1; t < TPS; t += 2) {   // t = 1,3,...,47
        MFMAC(accB, aA);                 // cell t in flight (tile t)
        LDA(aA, t + 1);                  // tile t+1 (<= 48)
        EXTRACT(accA, (u32)((t - 1) * 16));  // extract cell t-1
        MFMAC(accA, aA);                 // cell t+1 in flight
        if (t + 2 < TPS) LDA(aA, t + 2); // tile t+2
        EXTRACT(accB, (u32)(t * 16));    // extract cell t
    }
    EXTRACT(accA, (u32)((TPS - 1) * 16));    // cell 48

    // merge the 4 chains' top-4s -> exact stream top-4 (64 ops, once)
    float m1 = 0.f, m2 = 0.f, m3 = 0.f, m4 = 0.f;
    #pragma unroll
    for (int c = 0; c < 4; ++c) {
        float vals[4] = {ch1[c], ch2[c], ch3[c], ch4[c]};
        #pragma unroll
        for (int k = 0; k < 4; ++k) {
            float p_ = vals[k];
            m4 = FMED3(p_, m3, m4);
            m3 = FMED3(p_, m2, m3);
            m2 = FMED3(p_, m1, m2);
            m1 = fmaxf(p_, m1);
        }
    }

    // decode + write candidates: [b][n][split][hi][4]
    int n = nt * 32 + lo;
    size_t base = (((size_t)(b * N_ + n) * SPLIT + split) * 2 + hi) * LCAP;
    float bs[4] = {m1, m2, m3, m4};
    #pragma unroll
    for (int k = 0; k < 4; ++k) {
        u32 pb = __float_as_uint(bs[k]);
        int idx10 = (int)(pb & 1023u);
        int tl = idx10 >> 4, r = idx10 & 15;
        int m = (tbase + tl) * 32 + (r & 3) + ((r >> 2) << 3) + (hi << 2);
        cvals[base + k] = pb;
        cidx[base + k] = (u16)m;
    }
}

// ---------------------------------------------------------------------------
// Kernel 3: selective exact rescore. One wave per row, 1 candidate/lane.
// 3 wave-max rounds on noisy packed values -> t3; lanes with
// vn >= t3 - 0.125 (noise+grain ~0.04, 3x margin) recompute the
// bit-identical round-1 fp32 dot from contiguous fxT/fynT rows. Exact
// selection (tie: lower index) + exact weights -> absmax 0 preserved.
// ---------------------------------------------------------------------------
__global__ __launch_bounds__(256)
void rescore(const u32* __restrict__ cvals, const u16* __restrict__ cidx,
             const float* __restrict__ fxT, const float* __restrict__ fynT,
             const float* __restrict__ nyeps, const float* __restrict__ minf,
             const unsigned char* __restrict__ mask1b,
             const int* __restrict__ flags, float* __restrict__ out) {
    int gw = blockIdx.x * 4 + (threadIdx.x >> 6);    // row = b*N + n  (grid exact)
    int lane = threadIdx.x & 63;
    int b = gw / N_;

    float vn = __uint_as_float(cvals[(size_t)gw * CPR + lane]);
    int idx = cidx[(size_t)gw * CPR + lane];

    float cur = vn;
    float t3 = NEGINF;
    #pragma unroll
    for (int r = 0; r < 3; ++r) {
        float c = cur;
        #pragma unroll
        for (int off = 32; off >= 1; off >>= 1) c = fmaxf(c, __shfl_xor(c, off));
        t3 = c;
        cur = (cur == c) ? NEGINF : cur;
    }
    bool redo = (vn >= t3 - 0.125f);

    float rnk = NEGINF, wgt = 0.f;
    if (redo) {
        const float4* xq4 = (const float4*)(fxT + (size_t)gw * C_);
        const float4* fr4 = (const float4*)(fynT + ((size_t)b * N_ + idx) * C_);
        float a = 0.f;
        #pragma unroll
        for (int c4 = 0; c4 < 16; ++c4) {
            float4 xf = xq4[c4];
            float4 f  = fr4[c4];
            a = fmaf(xf.x, f.x, a);
            a = fmaf(xf.y, f.y, a);
            a = fmaf(xf.z, f.z, a);
            a = fmaf(xf.w, f.w, a);
        }
        rnk = a + minf[(size_t)b * N_ + idx];
        wgt = a * nyeps[(size_t)b * N_ + idx];
    }
    int midx = redo ? idx : 0x7fffffff;

    int wi[3]; float ww[3];
    #pragma unroll
    for (int r = 0; r < 3; ++r) {
        float cv = rnk; int ci = midx; float cw = wgt;
        #pragma unroll
        for (int off = 32; off >= 1; off >>= 1) {
            float ov = __shfl_xor(cv, off);
            int   oi = __shfl_xor(ci, off);
            float ow = __shfl_xor(cw, off);
            bool take = (ov > cv) || (ov == cv && oi < ci);
            cv = take ? ov : cv; ci = take ? oi : ci; cw = take ? ow : cw;
        }
        wi[r] = ci; ww[r] = cw;
        if (midx == ci) rnk = NEGINF;   // remove winner (and duplicates)
    }

    if (lane == 0) {
        float w0 = ww[0], w1 = ww[1], w2 = ww[2];
        float h0 = (float)(wi[0] / W_), h1 = (float)(wi[1] / W_), h2 = (float)(wi[2] / W_);
        float q0 = (float)(wi[0] % W_), q1 = (float)(wi[1] % W_), q2 = (float)(wi[2] % W_);
        float den = w0 + w1 + w2;
        float ph = (h0 * w0 + h1 * w1 + h2 * w2) / den;
        float pw = (q0 * w0 + q1 * w1 + q2 * w2) / den;
        bool m1v = flags[0] ? (mask1b[gw] != 0) : (((const int*)mask1b)[gw] != 0);
        out[2 * gw]     = m1v ? ph : -1.0f;
        out[2 * gw + 1] = m1v ? pw : -1.0f;
    }
}

// ---------------------------------------------------------------------------
// Kernel 4: slic gather.
// ---------------------------------------------------------------------------
__global__ void slic_gather(const float* __restrict__ spg,
                            const float* __restrict__ pred,
                            float* __restrict__ outg) {
    int t = blockIdx.x * blockDim.x + threadIdx.x;
    if (t >= B_ * S_ * G_) return;
    int b = t / (S_ * G_);
    float vh = spg[2 * t], vw = spg[2 * t + 1];
    int ph = (int)rintf(vh * (float)H_);
    int pw = (int)rintf(vw * (float)H_);
    ph = ph < 0 ? 0 : (ph > H_ - 1 ? H_ - 1 : ph);
    pw = pw < 0 ? 0 : (pw > H_ - 1 ? H_ - 1 : pw);
    int lin = ph * W_ + pw;
    outg[2 * t]     = pred[((size_t)b * N_ + lin) * 2]     / (float)H_;
    outg[2 * t + 1] = pred[((size_t)b * N_ + lin) * 2 + 1] / (float)H_;
}

extern "C" void kernel_launch(void* const* d_in, const int* in_sizes, int n_in,
                              void* d_out, int out_size, void* d_ws, size_t ws_size,
                              hipStream_t stream) {
    const float* img1 = (const float*)d_in[0];
    const float* img2 = (const float*)d_in[1];
    const void*  mask1 = d_in[2];
    const void*  mask2 = d_in[3];
    const float* spg = (const float*)d_in[4];
    float* out = (float*)d_out;

    char* ws = (char*)d_ws;
    size_t off = 0;
    int*   flags = (int*)(ws + off);            off += 256;
    float* fynT  = (float*)(ws + off);          off += (size_t)B_ * N_ * C_ * 4;       // 6.42 MB
    float* fxT   = (float*)(ws + off);          off += (size_t)B_ * N_ * C_ * 4;       // 6.42 MB
    f16*   fxq   = (f16*)(ws + off);            off += (size_t)B_ * NT * KS * 64 * 16; // 4.01 MB
    f16*   fynq  = (f16*)(ws + off);            off += (size_t)B_ * MT * KS * 64 * 16; // 4.01 MB
    float* nyeps = (float*)(ws + off);          off += (size_t)B_ * N_ * 4;
    float* minf  = (float*)(ws + off);          off += (size_t)B_ * N_ * 4;
    u32*   cvals = (u32*)(ws + off);            off += (size_t)B_ * N_ * CPR * 4;      // 6.42 MB
    u16*   cidx  = (u16*)(ws + off);            off += (size_t)B_ * N_ * CPR * 2;      // 3.21 MB

    detect_fmt<<<1, 1024, 0, stream>>>((const u32*)mask1, (const u32*)mask2,
                                       (B_ * N_) / 4, flags);
    dim3 gp((B_ * N_) / 256, 2);
    prep<<<gp, 256, 0, stream>>>(img1, img2, (const unsigned char*)mask2, flags,
                                 fxq, fxT, fynT, fynq, nyeps, minf);

    stage1<<<3136, 128, 0, stream>>>(fxq, fynq, cvals, cidx);

    rescore<<<(B_ * N_) / 4, 256, 0, stream>>>(
        cvals, cidx, fxT, fynT, nyeps, minf,
        (const unsigned char*)mask1, flags, out);

    slic_gather<<<(B_ * S_ * G_ + 255) / 256, 256, 0, stream>>>(
        spg, out, out + (size_t)B_ * N_ * 2);
}

// Round 13
// 153.732 us; speedup vs baseline: 1.0059x; 1.0059x over previous
//
#include <hip/hip_runtime.h>
#include <math.h>

typedef _Float16 f16;
typedef f16 f16x8 __attribute__((ext_vector_type(8)));
typedef float f32x16 __attribute__((ext_vector_type(16)));
typedef unsigned short u16;
typedef unsigned int u32;

#define B_ 2
#define C_ 64
#define KS 5             // K-steps of 16: 64 feats + mask(k=64) + bias(k=65) + pad
#define H_ 112
#define W_ 112
#define N_ 12544
#define S_ 50
#define G_ 120
#define MT 392           // m-tiles of 32
#define NT 392           // n-subtiles of 32
#define SPLIT 8
#define TPS 49           // m-tiles per split
#define LCAP 4           // per-lane-half top-4 (exact, branch-free)
#define CPR (SPLIT*2*LCAP) // 64 candidates per row -> 1 per lane in rescore

#define NEGINF (-__builtin_inff())
#define FMED3 __builtin_amdgcn_fmed3f

union U16B { uint4 u; f16x8 h; f16 e[8]; };

// ---------------------------------------------------------------------------
// Kernel 0: bool-mask format detect (byte vs int32), vectorized word test.
// ---------------------------------------------------------------------------
__global__ void detect_fmt(const u32* __restrict__ m1, const u32* __restrict__ m2,
                           int nw, int* __restrict__ flags) {
    __shared__ u32 s[2];
    if (threadIdx.x == 0) { s[0] = 0; s[1] = 0; }
    __syncthreads();
    u32 a = 0, bb = 0;
    for (int i = threadIdx.x; i < nw; i += blockDim.x) {
        a  |= m1[i] & 0xFFFFFF00u;
        bb |= m2[i] & 0xFFFFFF00u;
    }
    if (a)  atomicOr(&s[0], 1u);
    if (bb) atomicOr(&s[1], 1u);
    __syncthreads();
    if (threadIdx.x == 0) { flags[0] = s[0] ? 1 : 0; flags[1] = s[1] ? 1 : 0; }
}

// ---------------------------------------------------------------------------
// Kernel 1 (fused): y==0 -> src features: fp16 frag-ordered fxq (k=64/65
// channels = 1.0) AND contiguous fp32 fxT rows. y==1 -> dst features: fp32
// fynT rows (bitwise same math as round 1), fp16 frag-ordered fynq with
// mask channel (k=64: 0 valid / -96 masked) and bias channel (k=65: +128),
// nyeps, minf.
// ---------------------------------------------------------------------------
__global__ void prep(const float* __restrict__ fx, const float* __restrict__ fy,
                     const unsigned char* __restrict__ mask2b,
                     const int* __restrict__ flags,
                     f16* __restrict__ fxq, float* __restrict__ fxT,
                     float* __restrict__ fynT, f16* __restrict__ fynq,
                     float* __restrict__ nyeps, float* __restrict__ minf) {
    int t = blockIdx.x * blockDim.x + threadIdx.x;   // t = b*N + pixel
    if (t >= B_ * N_) return;
    int b = t / N_, m = t - b * N_;
    int tile = m >> 5, r = m & 31;

    if (blockIdx.y == 0) {
        const float* src = fx + (size_t)b * C_ * N_ + m;
        float v[64];
        #pragma unroll
        for (int c = 0; c < C_; ++c) v[c] = src[(size_t)c * N_];

        float4* xT = (float4*)(fxT + (size_t)t * C_);
        #pragma unroll
        for (int c4 = 0; c4 < 16; ++c4)
            xT[c4] = make_float4(v[c4*4], v[c4*4+1], v[c4*4+2], v[c4*4+3]);

        uint4* q4 = (uint4*)fxq;
        size_t cb = (size_t)(b * NT + tile) * KS * 64;
        #pragma unroll
        for (int ks = 0; ks < KS; ++ks) {
            #pragma unroll
            for (int hi = 0; hi < 2; ++hi) {
                U16B tmp;
                #pragma unroll
                for (int i = 0; i < 8; ++i) {
                    int k = 16 * ks + 8 * hi + i;
                    float val = (k < 64) ? v[k] : ((k <= 65) ? 1.0f : 0.0f);
                    tmp.e[i] = (f16)val;
                }
                q4[cb + (size_t)ks * 64 + hi * 32 + r] = tmp.u;
            }
        }
    } else {
        const float* src = fy + (size_t)b * C_ * N_ + m;
        float v[64];
        float ss = 0.f;
        #pragma unroll
        for (int c = 0; c < C_; ++c) { v[c] = src[(size_t)c * N_]; ss = fmaf(v[c], v[c], ss); }
        float ny = sqrtf(ss) + 1e-12f;
        nyeps[t] = ny;
        bool valid = flags[1] ? (mask2b[t] != 0) : (((const int*)mask2b)[t] != 0);
        minf[t] = valid ? 0.0f : NEGINF;
        float mval = valid ? 0.0f : -96.0f;

        float* dT = fynT + (size_t)t * C_;
        #pragma unroll
        for (int c = 0; c < C_; ++c) dT[c] = v[c] / ny;   // round-1 arithmetic

        uint4* q4 = (uint4*)fynq;
        size_t cb = (size_t)(b * MT + tile) * KS * 64;
        #pragma unroll
        for (int ks = 0; ks < KS; ++ks) {
            #pragma unroll
            for (int hi = 0; hi < 2; ++hi) {
                U16B tmp;
                #pragma unroll
                for (int i = 0; i < 8; ++i) {
                    int k = 16 * ks + 8 * hi + i;
                    float val = (k < 64) ? (v[k] / ny)
                              : ((k == 64) ? mval : ((k == 65) ? 128.0f : 0.0f));
                    tmp.e[i] = (f16)val;
                }
                q4[cb + (size_t)ks * 64 + hi * 32 + r] = tmp.u;
            }
        }
    }
}

// ---------------------------------------------------------------------------
// Kernel 2: MFMA candidate pass — LEAN TLP variant. The R5-R12 invariant
// (~110 us regardless of schedule) is latency holes: ~900 cyc/SIMD/cell vs
// ~260 cyc of issue work, with only 2.3 waves/SIMD resident (register-fat
// waves: ping-pong acc + double A-buffer + zvec ~ 130-160 unified regs).
// This variant slims the wave to ~86 regs (single acc re-zeroed per cell,
// single A buffer with 1-deep prefetch, no zvec, builtins not asm) so 5
// waves/SIMD can be resident: TLP hides the per-cell dependent chain
// (5 MFMAs -> extract -> vmcnt) that ILP tricks failed to hide.
// Flat grid, panel = gid & 15 -> XCD L2 affinity (each XCD serves 2 fynq
// panels, 490 KB, L2-resident). 4 independent med3 top-4 chains (reg r ->
// chain r&3), merged at the end == exact stream top-4 (identical candidate
// set to R10-R12). 10-bit (tile*16+reg) index in mantissa low bits (scores
// positive via +128 bias channel -> f32 order == u32 order).
// ---------------------------------------------------------------------------
#define LDA(dst, t) { _Pragma("unroll") \
    for (int ks = 0; ks < KS; ++ks) { \
        U16B u_; u_.u = fyb[((size_t)(t) * KS + ks) * 64]; dst[ks] = u_.h; } }

#define MFMAC(acc, a) { acc = (f32x16){}; \
    _Pragma("unroll") \
    for (int ks = 0; ks < KS; ++ks) \
        acc = __builtin_amdgcn_mfma_f32_32x32x16_f16(a[ks], bfr[ks], acc, 0, 0, 0); }

#define EXTRACT(acc, bse) { \
    _Pragma("unroll") \
    for (int r = 0; r < 16; ++r) { \
        const int c_ = r & 3; \
        u32 pb_ = (__float_as_uint(acc[r]) & VMASK) | ((bse) + (u32)r); \
        float p_ = __uint_as_float(pb_); \
        ch4[c_] = FMED3(p_, ch3[c_], ch4[c_]); \
        ch3[c_] = FMED3(p_, ch2[c_], ch3[c_]); \
        ch2[c_] = FMED3(p_, ch1[c_], ch2[c_]); \
        ch1[c_] = fmaxf(p_, ch1[c_]); } }

__global__ __launch_bounds__(256, 5)
void stage1(const f16* __restrict__ fxq, const f16* __restrict__ fynq,
            u32* __restrict__ cvals, u16* __restrict__ cidx) {
    const int tid = threadIdx.x;
    const int lane = tid & 63, w = tid >> 6;
    const int lo = lane & 31, hi = lane >> 5;
    const int gid = blockIdx.x;          // 0..1567
    const int panel = gid & 15;          // (b<<3)|split -> XCD affinity
    const int b = panel >> 3, split = panel & 7;
    const int nt = (gid >> 4) * 4 + w;   // 0..391
    const int tbase = split * TPS;

    const uint4* fxq4 = (const uint4*)fxq;
    const uint4* fyb  = (const uint4*)fynq + ((size_t)(b * MT + tbase) * KS) * 64 + lane;

    // pack mask pinned in a VGPR so (bits & VMASK) | s_idx fuses to v_and_or_b32
    u32 VMASK;
    asm("v_mov_b32 %0, 0xFFFFFC00" : "=v"(VMASK));

    // resident B-fragments: fx for this wave's n-subtile
    f16x8 bfr[KS];
    #pragma unroll
    for (int ks = 0; ks < KS; ++ks) {
        U16B u; u.u = fxq4[((size_t)((b * NT + nt) * KS + ks)) * 64 + lane];
        bfr[ks] = u.h;
    }

    // 4 independent top-4 chains (reg r -> chain r&3)
    float ch1[4] = {0.f, 0.f, 0.f, 0.f};
    float ch2[4] = {0.f, 0.f, 0.f, 0.f};
    float ch3[4] = {0.f, 0.f, 0.f, 0.f};
    float ch4[4] = {0.f, 0.f, 0.f, 0.f};

    f16x8 aA[KS];
    f32x16 acc;

    LDA(aA, 0);
    #pragma unroll 1
    for (int t = 0; t < TPS; ++t) {
        MFMAC(acc, aA);                  // 5 MFMAs read aA at issue (in-order)
        if (t + 1 < TPS) LDA(aA, t + 1); // prefetch overlaps MFMA pipe + extract
        EXTRACT(acc, (u32)(t * 16));     // VALU while loads fly
    }

    // merge the 4 chains' top-4s -> exact stream top-4 (64 ops, once)
    float m1 = 0.f, m2 = 0.f, m3 = 0.f, m4 = 0.f;
    #pragma unroll
    for (int c = 0; c < 4; ++c) {
        float vals[4] = {ch1[c], ch2[c], ch3[c], ch4[c]};
        #pragma unroll
        for (int k = 0; k < 4; ++k) {
            float p_ = vals[k];
            m4 = FMED3(p_, m3, m4);
            m3 = FMED3(p_, m2, m3);
            m2 = FMED3(p_, m1, m2);
            m1 = fmaxf(p_, m1);
        }
    }

    // decode + write candidates: [b][n][split][hi][4]
    int n = nt * 32 + lo;
    size_t base = (((size_t)(b * N_ + n) * SPLIT + split) * 2 + hi) * LCAP;
    float bs[4] = {m1, m2, m3, m4};
    #pragma unroll
    for (int k = 0; k < 4; ++k) {
        u32 pb = __float_as_uint(bs[k]);
        int idx10 = (int)(pb & 1023u);
        int tl = idx10 >> 4, r = idx10 & 15;
        int m = (tbase + tl) * 32 + (r & 3) + ((r >> 2) << 3) + (hi << 2);
        cvals[base + k] = pb;
        cidx[base + k] = (u16)m;
    }
}

// ---------------------------------------------------------------------------
// Kernel 3: selective exact rescore. One wave per row, 1 candidate/lane.
// 3 wave-max rounds on noisy packed values -> t3; lanes with
// vn >= t3 - 0.125 (noise+grain ~0.04, 3x margin) recompute the
// bit-identical round-1 fp32 dot from contiguous fxT/fynT rows. Exact
// selection (tie: lower index) + exact weights -> absmax 0 preserved.
// ---------------------------------------------------------------------------
__global__ __launch_bounds__(256)
void rescore(const u32* __restrict__ cvals, const u16* __restrict__ cidx,
             const float* __restrict__ fxT, const float* __restrict__ fynT,
             const float* __restrict__ nyeps, const float* __restrict__ minf,
             const unsigned char* __restrict__ mask1b,
             const int* __restrict__ flags, float* __restrict__ out) {
    int gw = blockIdx.x * 4 + (threadIdx.x >> 6);    // row = b*N + n  (grid exact)
    int lane = threadIdx.x & 63;
    int b = gw / N_;

    float vn = __uint_as_float(cvals[(size_t)gw * CPR + lane]);
    int idx = cidx[(size_t)gw * CPR + lane];

    float cur = vn;
    float t3 = NEGINF;
    #pragma unroll
    for (int r = 0; r < 3; ++r) {
        float c = cur;
        #pragma unroll
        for (int off = 32; off >= 1; off >>= 1) c = fmaxf(c, __shfl_xor(c, off));
        t3 = c;
        cur = (cur == c) ? NEGINF : cur;
    }
    bool redo = (vn >= t3 - 0.125f);

    float rnk = NEGINF, wgt = 0.f;
    if (redo) {
        const float4* xq4 = (const float4*)(fxT + (size_t)gw * C_);
        const float4* fr4 = (const float4*)(fynT + ((size_t)b * N_ + idx) * C_);
        float a = 0.f;
        #pragma unroll
        for (int c4 = 0; c4 < 16; ++c4) {
            float4 xf = xq4[c4];
            float4 f  = fr4[c4];
            a = fmaf(xf.x, f.x, a);
            a = fmaf(xf.y, f.y, a);
            a = fmaf(xf.z, f.z, a);
            a = fmaf(xf.w, f.w, a);
        }
        rnk = a + minf[(size_t)b * N_ + idx];
        wgt = a * nyeps[(size_t)b * N_ + idx];
    }
    int midx = redo ? idx : 0x7fffffff;

    int wi[3]; float ww[3];
    #pragma unroll
    for (int r = 0; r < 3; ++r) {
        float cv = rnk; int ci = midx; float cw = wgt;
        #pragma unroll
        for (int off = 32; off >= 1; off >>= 1) {
            float ov = __shfl_xor(cv, off);
            int   oi = __shfl_xor(ci, off);
            float ow = __shfl_xor(cw, off);
            bool take = (ov > cv) || (ov == cv && oi < ci);
            cv = take ? ov : cv; ci = take ? oi : ci; cw = take ? ow : cw;
        }
        wi[r] = ci; ww[r] = cw;
        if (midx == ci) rnk = NEGINF;   // remove winner (and duplicates)
    }

    if (lane == 0) {
        float w0 = ww[0], w1 = ww[1], w2 = ww[2];
        float h0 = (float)(wi[0] / W_), h1 = (float)(wi[1] / W_), h2 = (float)(wi[2] / W_);
        float q0 = (float)(wi[0] % W_), q1 = (float)(wi[1] % W_), q2 = (float)(wi[2] % W_);
        float den = w0 + w1 + w2;
        float ph = (h0 * w0 + h1 * w1 + h2 * w2) / den;
        float pw = (q0 * w0 + q1 * w1 + q2 * w2) / den;
        bool m1v = flags[0] ? (mask1b[gw] != 0) : (((const int*)mask1b)[gw] != 0);
        out[2 * gw]     = m1v ? ph : -1.0f;
        out[2 * gw + 1] = m1v ? pw : -1.0f;
    }
}

// ---------------------------------------------------------------------------
// Kernel 4: slic gather.
// ---------------------------------------------------------------------------
__global__ void slic_gather(const float* __restrict__ spg,
                            const float* __restrict__ pred,
                            float* __restrict__ outg) {
    int t = blockIdx.x * blockDim.x + threadIdx.x;
    if (t >= B_ * S_ * G_) return;
    int b = t / (S_ * G_);
    float vh = spg[2 * t], vw = spg[2 * t + 1];
    int ph = (int)rintf(vh * (float)H_);
    int pw = (int)rintf(vw * (float)H_);
    ph = ph < 0 ? 0 : (ph > H_ - 1 ? H_ - 1 : ph);
    pw = pw < 0 ? 0 : (pw > H_ - 1 ? H_ - 1 : pw);
    int lin = ph * W_ + pw;
    outg[2 * t]     = pred[((size_t)b * N_ + lin) * 2]     / (float)H_;
    outg[2 * t + 1] = pred[((size_t)b * N_ + lin) * 2 + 1] / (float)H_;
}

extern "C" void kernel_launch(void* const* d_in, const int* in_sizes, int n_in,
                              void* d_out, int out_size, void* d_ws, size_t ws_size,
                              hipStream_t stream) {
    const float* img1 = (const float*)d_in[0];
    const float* img2 = (const float*)d_in[1];
    const void*  mask1 = d_in[2];
    const void*  mask2 = d_in[3];
    const float* spg = (const float*)d_in[4];
    float* out = (float*)d_out;

    char* ws = (char*)d_ws;
    size_t off = 0;
    int*   flags = (int*)(ws + off);            off += 256;
    float* fynT  = (float*)(ws + off);          off += (size_t)B_ * N_ * C_ * 4;       // 6.42 MB
    float* fxT   = (float*)(ws + off);          off += (size_t)B_ * N_ * C_ * 4;       // 6.42 MB
    f16*   fxq   = (f16*)(ws + off);            off += (size_t)B_ * NT * KS * 64 * 16; // 4.01 MB
    f16*   fynq  = (f16*)(ws + off);            off += (size_t)B_ * MT * KS * 64 * 16; // 4.01 MB
    float* nyeps = (float*)(ws + off);          off += (size_t)B_ * N_ * 4;
    float* minf  = (float*)(ws + off);          off += (size_t)B_ * N_ * 4;
    u32*   cvals = (u32*)(ws + off);            off += (size_t)B_ * N_ * CPR * 4;      // 6.42 MB
    u16*   cidx  = (u16*)(ws + off);            off += (size_t)B_ * N_ * CPR * 2;      // 3.21 MB

    detect_fmt<<<1, 1024, 0, stream>>>((const u32*)mask1, (const u32*)mask2,
                                       (B_ * N_) / 4, flags);
    dim3 gp((B_ * N_) / 256, 2);
    prep<<<gp, 256, 0, stream>>>(img1, img2, (const unsigned char*)mask2, flags,
                                 fxq, fxT, fynT, fynq, nyeps, minf);

    stage1<<<1568, 256, 0, stream>>>(fxq, fynq, cvals, cidx);

    rescore<<<(B_ * N_) / 4, 256, 0, stream>>>(
        cvals, cidx, fxT, fynT, nyeps, minf,
        (const unsigned char*)mask1, flags, out);

    slic_gather<<<(B_ * S_ * G_ + 255) / 256, 256, 0, stream>>>(
        spg, out, out + (size_t)B_ * N_ * 2);
}